// Round 3
// baseline (159.511 us; speedup 1.0000x reference)
//
#include <hip/hip_runtime.h>

// y[n,f] = sum_p w_table[widx[n],p] * pool[idx[n,p],f]
// pool = concat(values0, values1). N=500000, P=16, F=32, M=200000, K=10000.
// Strategy: 8 lanes per neuron, one float4 per lane (full 128B row per 8 lanes,
// perfectly coalesced). Issue ALL 16 row-gathers before the FMA chain to
// maximize memory-level parallelism (latency/queueing-bound regime).

#define PP 16
#define FF 32

typedef float  f32x4 __attribute__((ext_vector_type(4)));
typedef int    i32x4 __attribute__((ext_vector_type(4)));

__global__ __launch_bounds__(256) void linear_gather_kernel(
    const float* __restrict__ values0,
    const float* __restrict__ values1,
    const float* __restrict__ w_table,
    const int*   __restrict__ idx,
    const int*   __restrict__ widx,
    float*       __restrict__ out,
    int N, int M)
{
    int t = blockIdx.x * blockDim.x + threadIdx.x;
    int n  = t >> 3;   // 8 lanes per neuron
    int f4 = t & 7;    // which float4 of the 32-float row
    if (n >= N) return;

    // Vector-load the 16 indices (64B) and 16 weights (64B); broadcast across
    // the 8 lanes of this neuron.
    const i32x4* irow4 = reinterpret_cast<const i32x4*>(idx + (long)n * PP);
    const f32x4* wrow4 = reinterpret_cast<const f32x4*>(w_table + (long)widx[n] * PP);

    i32x4 i0 = irow4[0], i1 = irow4[1], i2 = irow4[2], i3 = irow4[3];
    f32x4 w0 = wrow4[0], w1 = wrow4[1], w2 = wrow4[2], w3 = wrow4[3];

    int ii[PP] = { i0.x, i0.y, i0.z, i0.w,  i1.x, i1.y, i1.z, i1.w,
                   i2.x, i2.y, i2.z, i2.w,  i3.x, i3.y, i3.z, i3.w };
    float ww[PP] = { w0.x, w0.y, w0.z, w0.w,  w1.x, w1.y, w1.z, w1.w,
                     w2.x, w2.y, w2.z, w2.w,  w3.x, w3.y, w3.z, w3.w };

    // Issue all 16 gathers first — keep 16 dwordx4 loads in flight per thread.
    f32x4 v[PP];
#pragma unroll
    for (int p = 0; p < PP; ++p) {
        int i = ii[p];
        const float* src = (i < M) ? (values0 + (long)i * FF)
                                   : (values1 + (long)(i - M) * FF);
        v[p] = *reinterpret_cast<const f32x4*>(src + f4 * 4);
    }

    // FMA chain after all loads are issued.
    f32x4 acc = (f32x4)(0.f);
#pragma unroll
    for (int p = 0; p < PP; ++p) {
        acc.x = fmaf(ww[p], v[p].x, acc.x);
        acc.y = fmaf(ww[p], v[p].y, acc.y);
        acc.z = fmaf(ww[p], v[p].z, acc.z);
        acc.w = fmaf(ww[p], v[p].w, acc.w);
    }

    // Streamed output — nontemporal store to avoid evicting pool rows from L2.
    __builtin_nontemporal_store(acc, reinterpret_cast<f32x4*>(out) + (long)n * 8 + f4);
}

extern "C" void kernel_launch(void* const* d_in, const int* in_sizes, int n_in,
                              void* d_out, int out_size, void* d_ws, size_t ws_size,
                              hipStream_t stream) {
    const float* values0 = (const float*)d_in[0];
    const float* values1 = (const float*)d_in[1];
    const float* w_table = (const float*)d_in[2];
    const int*   idx     = (const int*)d_in[3];
    const int*   widx    = (const int*)d_in[4];
    float*       out     = (float*)d_out;

    const int N = in_sizes[4];          // widx has N elements
    const int M = in_sizes[0] / FF;     // values0 rows

    long total_threads = (long)N * 8;
    int  block = 256;
    int  grid  = (int)((total_threads + block - 1) / block);

    linear_gather_kernel<<<grid, block, 0, stream>>>(
        values0, values1, w_table, idx, widx, out, N, M);
}